// Round 4
// baseline (1510.201 us; speedup 1.0000x reference)
//
#include <hip/hip_runtime.h>

// CacheFuser on MI355X (gfx950) — round 4.
// Root cause of r2/r3: LLVM sizes the reg budget from LDS-limited occupancy
// (128KB LDS -> 2 waves/SIMD -> 256 regs), and peak demand was ~260 -> spill
// (620MB scratch traffic in WRITE_SIZE). Fix: shrink working set, not bound.
//  * BM=64, wave tile 64p x 32q -> acc[4][2]=32 regs; stage v[8]=32 regs.
//  * LDS 2x32KB -> 2 blocks/CU (16 waves/CU) -> cross-block HBM/MFMA overlap.
//  * __launch_bounds__(512,4): budget 128, demand ~115.
//  * W panels direct from L2 (k-tile-major bf16 in d_ws), no k-loop barriers.

typedef unsigned int  u32;
typedef unsigned short u16;
typedef __attribute__((ext_vector_type(8))) short bf16x8;   // 8 x bf16
typedef __attribute__((ext_vector_type(4))) float f32x4;

#define LL   8
#define NN   4
#define HH   256
#define RPL  8192            // rows per layer = B*S
#define BM   64              // rows per block

// d_ws layout: per layer 655360 u16; per matrix: k-tile-major 8192-u16 tiles,
// tile kt holds W^T[p][kt*32..kt*32+32) as [p][32] row-major.
#define LSTRIDE 655360
#define O_AKW1 0
#define O_AKW2 65536
#define O_AVW1 131072
#define O_AVW2 196608
#define O_FKW1 262144        // K=512 -> 16 tiles (0..7 recv half, 8..15 agg half)
#define O_FKW2 393216
#define O_FVW1 458752
#define O_FVW2 589824
// total 5242880 u16 = 10485760 B in d_ws

__device__ __forceinline__ u32 f2bf(float f) {
  u32 u = __builtin_bit_cast(u32, f);
  return (u + 0x7fffu + ((u >> 16) & 1u)) >> 16;   // RNE
}

// ---------------- prep: W[k][p] f32 -> k-tile-major bf16 W^T tiles -----------
__global__ __launch_bounds__(256) void prep_wt_k(
    const float* __restrict__ s0, const float* __restrict__ s1,
    const float* __restrict__ s2, const float* __restrict__ s3,
    const float* __restrict__ s4, const float* __restrict__ s5,
    const float* __restrict__ s6, const float* __restrict__ s7,
    u16* __restrict__ wt)
{
  __shared__ float tile[32][33];
  const int mat = blockIdx.z, l = blockIdx.y, t = blockIdx.x;
  const float* src; int off, K;
  switch (mat) {
    case 0: src = s0; off = O_AKW1; K = 256; break;
    case 1: src = s1; off = O_AKW2; K = 256; break;
    case 2: src = s2; off = O_AVW1; K = 256; break;
    case 3: src = s3; off = O_AVW2; K = 256; break;
    case 4: src = s4; off = O_FKW1; K = 512; break;
    case 5: src = s5; off = O_FKW2; K = 256; break;
    case 6: src = s6; off = O_FVW1; K = 512; break;
    default: src = s7; off = O_FVW2; K = 256; break;
  }
  const int ntk = K >> 5;
  if (t >= ntk * 8) return;                 // 8 p-tiles of 32
  const int tk = t % ntk, tp = t / ntk;
  src += (size_t)l * K * HH;
  u16* dst = wt + (size_t)l * LSTRIDE + off;
  #pragma unroll
  for (int i = 0; i < 4; ++i) {
    int idx = threadIdx.x + i * 256;
    int r = idx >> 5, c = idx & 31;        // r = k-local, c = p-local
    tile[r][c] = src[(size_t)(tk * 32 + r) * HH + tp * 32 + c];
  }
  __syncthreads();
  const int pl = threadIdx.x >> 3, kq = threadIdx.x & 7;
  const int p = tp * 32 + pl;
  ushort4 o;
  o.x = (u16)f2bf(tile[kq * 4 + 0][pl]);
  o.y = (u16)f2bf(tile[kq * 4 + 1][pl]);
  o.z = (u16)f2bf(tile[kq * 4 + 2][pl]);
  o.w = (u16)f2bf(tile[kq * 4 + 3][pl]);
  *(ushort4*)(dst + (size_t)tk * 8192 + p * 32 + kq * 4) = o;
}

// ---------------- main kernel helpers ---------------------------------------
__device__ __forceinline__ void zero42(f32x4 (&a)[4][2]) {
  f32x4 z = {0.f, 0.f, 0.f, 0.f};
  #pragma unroll
  for (int i = 0; i < 4; ++i) {
    a[i][0] = z; a[i][1] = z;
  }
}

// D[p][q] += W^T[p][k] * Act[q][k] over K=256 (8 k-tiles), no barriers inside.
// a-frags: direct global (L2/L1) loads; b-frags: swizzled LDS reads.
__device__ __forceinline__ void gemm8(
    f32x4 (&acc)[4][2], const u16* __restrict__ wtile,
    const u16* __restrict__ act, int wp, int wq, int lr, int g)
{
  const u16* wl = wtile + (wp * 64 + lr) * 32 + g * 8;  // +fp*512, +kt*8192
  #pragma unroll
  for (int kt = 0; kt < 8; ++kt) {
    bf16x8 a[4];
    #pragma unroll
    for (int fp = 0; fp < 4; ++fp)
      a[fp] = *(const bf16x8*)(wl + kt * 8192 + fp * 512);
    bf16x8 b[2];
    #pragma unroll
    for (int fq = 0; fq < 2; ++fq) {
      int q = wq * 32 + fq * 16 + lr;
      int k = (kt * 32 + g * 8) ^ ((q & 7) << 3);
      b[fq] = *(const bf16x8*)(act + q * HH + k);
    }
    #pragma unroll
    for (int fp = 0; fp < 4; ++fp)
      #pragma unroll
      for (int fq = 0; fq < 2; ++fq)
        acc[fp][fq] = __builtin_amdgcn_mfma_f32_16x16x32_bf16(a[fp], b[fq], acc[fp][fq], 0, 0, 0);
  }
}

// Per-thread register staging of a [64][256] f32 tile (T14 split): 8 float4.
struct StageRegs { float4 v[8]; };

__device__ __forceinline__ void stageLoad(StageRegs& r, const float* __restrict__ src, int tid) {
  #pragma unroll
  for (int i = 0; i < 8; ++i)
    r.v[i] = *(const float4*)(src + (tid + i * 512) * 4);   // fully coalesced sweeps
}

__device__ __forceinline__ void stageWrite(u16* dst, const StageRegs& r, int tid) {
  #pragma unroll
  for (int i = 0; i < 8; ++i) {
    int idx = tid + i * 512;             // float4 index in [0,4096)
    int q = idx >> 6, c = (idx & 63) * 4;
    const float4& x = r.v[i];
    ushort4 o;
    o.x = (u16)f2bf(x.x); o.y = (u16)f2bf(x.y);
    o.z = (u16)f2bf(x.z); o.w = (u16)f2bf(x.w);
    *(ushort4*)(dst + q * HH + (c ^ ((q & 7) << 3))) = o;
  }
}

// acc -> swizzled bf16 LDS: v = [relu?](acc + bscale*bias) * post
__device__ __forceinline__ void epiLds(
    u16* buf, f32x4 (&acc)[4][2], const float* __restrict__ bias,
    float bscale, float post, bool doRelu, int wp, int wq, int lr, int g)
{
  #pragma unroll
  for (int fp = 0; fp < 4; ++fp) {
    int p0 = wp * 64 + fp * 16 + g * 4;
    float4 bv = *(const float4*)(bias + p0);
    #pragma unroll
    for (int fq = 0; fq < 2; ++fq) {
      int q = wq * 32 + fq * 16 + lr;
      float v0 = acc[fp][fq][0] + bscale * bv.x;
      float v1 = acc[fp][fq][1] + bscale * bv.y;
      float v2 = acc[fp][fq][2] + bscale * bv.z;
      float v3 = acc[fp][fq][3] + bscale * bv.w;
      if (doRelu) {
        v0 = fmaxf(v0, 0.f); v1 = fmaxf(v1, 0.f);
        v2 = fmaxf(v2, 0.f); v3 = fmaxf(v3, 0.f);
      }
      ushort4 o;
      o.x = (u16)f2bf(v0 * post); o.y = (u16)f2bf(v1 * post);
      o.z = (u16)f2bf(v2 * post); o.w = (u16)f2bf(v3 * post);
      *(ushort4*)(buf + q * HH + (p0 ^ ((q & 7) << 3))) = o;
    }
  }
}

// out = recv + gate*(acc + bias)
__device__ __forceinline__ void epiOut(
    f32x4 (&acc)[4][2], const float* __restrict__ bias,
    const float* __restrict__ recv, float* __restrict__ outp,
    float gate, int wp, int wq, int lr, int g)
{
  #pragma unroll
  for (int fp = 0; fp < 4; ++fp) {
    int p0 = wp * 64 + fp * 16 + g * 4;
    float4 bv = *(const float4*)(bias + p0);
    #pragma unroll
    for (int fq = 0; fq < 2; ++fq) {
      int q = wq * 32 + fq * 16 + lr;
      float4 rv = *(const float4*)(recv + (size_t)q * HH + p0);
      float4 ov;
      ov.x = rv.x + gate * (acc[fp][fq][0] + bv.x);
      ov.y = rv.y + gate * (acc[fp][fq][1] + bv.y);
      ov.z = rv.z + gate * (acc[fp][fq][2] + bv.z);
      ov.w = rv.w + gate * (acc[fp][fq][3] + bv.w);
      *(float4*)(outp + (size_t)q * HH + p0) = ov;
    }
  }
}

__global__ __launch_bounds__(512, 4) void CacheFuser_73873437491748_kernel(
    const float* __restrict__ recv_k, const float* __restrict__ recv_v,
    const float* __restrict__ shar_k, const float* __restrict__ shar_v,
    const float* __restrict__ ew, const float* __restrict__ alpha,
    const float* __restrict__ ak_b1, const float* __restrict__ ak_b2,
    const float* __restrict__ av_b1, const float* __restrict__ av_b2,
    const float* __restrict__ fk_b1, const float* __restrict__ fk_b2,
    const float* __restrict__ fv_b1, const float* __restrict__ fv_b2,
    const u16* __restrict__ wt, float* __restrict__ out)
{
  __shared__ u16 B0[BM * HH];   // 32 KB, swizzled (e ^= (q&7)<<3)
  __shared__ u16 B1[BM * HH];   // 32 KB

  const int bid = blockIdx.x;
  const int l = bid & 7, t = bid >> 3;          // layer <-> XCD affinity
  const int tid = threadIdx.x;
  const int w = tid >> 6, lane = tid & 63, lr = lane & 15, g = lane >> 4;
  const int wp = w & 3, wq = w >> 2;

  const size_t row0 = (size_t)t * BM;
  const u16* lw = wt + (size_t)l * LSTRIDE;
  const float gate = 1.f / (1.f + __expf(-2.f * alpha[l]));
  const float* ewl = ew + l * NN;

  #pragma unroll 1
  for (int path = 0; path < 2; ++path) {
    const float* recvB = (path ? recv_v : recv_k) + ((size_t)l * RPL + row0) * HH;
    const float* sharB = (path ? shar_v : shar_k) + ((size_t)l * NN * RPL + row0) * HH;
    const u16* W1  = lw + (path ? O_AVW1 : O_AKW1);
    const u16* W2  = lw + (path ? O_AVW2 : O_AKW2);
    const u16* FW1 = lw + (path ? O_FVW1 : O_FKW1);
    const u16* FW2 = lw + (path ? O_FVW2 : O_FKW2);
    const float* b1  = (path ? av_b1 : ak_b1) + l * HH;
    const float* b2  = (path ? av_b2 : ak_b2) + l * HH;
    const float* fb1 = (path ? fv_b1 : fk_b1) + l * HH;
    const float* fb2 = (path ? fv_b2 : fk_b2) + l * HH;
    float* outp = out + ((size_t)(path * LL + l) * RPL + row0) * HH;

    StageRegs v;
    stageLoad(v, sharB, tid);                       // sharer 0
    f32x4 agg[4][2]; zero42(agg);
    float sS = 0.f;

    #pragma unroll 1
    for (int n = 0; n < NN; ++n) {
      float sn = ewl[n] * 0.25f; sS += sn;
      stageWrite(B0, v, tid);
      __syncthreads();
      f32x4 h[4][2]; zero42(h);
      gemm8(h, W1, B0, wp, wq, lr, g);
      epiLds(B1, h, b1, 1.f, sn, true, wp, wq, lr, g);   // B1 = sn*relu(h+b1)
      __syncthreads();
      stageLoad(v, (n < 3) ? sharB + (size_t)(n + 1) * RPL * HH : recvB, tid);
      gemm8(agg, W2, B1, wp, wq, lr, g);                 // agg += W2 * B1
    }
    epiLds(B0, agg, b2, sS, 1.f, false, wp, wq, lr, g);  // B0 = agg + sS*b2
    __syncthreads();
    stageWrite(B1, v, tid);                              // B1 = recv (bf16)
    __syncthreads();
    f32x4 h[4][2]; zero42(h);
    gemm8(h, FW1 + 8 * 8192, B0, wp, wq, lr, g);         // agg half (c>=256)
    gemm8(h, FW1, B1, wp, wq, lr, g);                    // recv half (c<256)
    __syncthreads();
    epiLds(B0, h, fb1, 1.f, 1.f, true, wp, wq, lr, g);
    __syncthreads();
    f32x4 dd[4][2]; zero42(dd);
    gemm8(dd, FW2, B0, wp, wq, lr, g);
    epiOut(dd, fb2, recvB, outp, gate, wp, wq, lr, g);
    __syncthreads();
  }
}

extern "C" void kernel_launch(void* const* d_in, const int* in_sizes, int n_in,
                              void* d_out, int out_size, void* d_ws, size_t ws_size,
                              hipStream_t stream)
{
  const float* recv_k = (const float*)d_in[0];
  const float* recv_v = (const float*)d_in[1];
  const float* shar_k = (const float*)d_in[2];
  const float* shar_v = (const float*)d_in[3];
  const float* ew     = (const float*)d_in[4];
  const float* alpha  = (const float*)d_in[5];
  const float* ak_w1 = (const float*)d_in[6];  const float* ak_b1 = (const float*)d_in[7];
  const float* ak_w2 = (const float*)d_in[8];  const float* ak_b2 = (const float*)d_in[9];
  const float* av_w1 = (const float*)d_in[10]; const float* av_b1 = (const float*)d_in[11];
  const float* av_w2 = (const float*)d_in[12]; const float* av_b2 = (const float*)d_in[13];
  const float* fk_w1 = (const float*)d_in[14]; const float* fk_b1 = (const float*)d_in[15];
  const float* fk_w2 = (const float*)d_in[16]; const float* fk_b2 = (const float*)d_in[17];
  const float* fv_w1 = (const float*)d_in[18]; const float* fv_b1 = (const float*)d_in[19];
  const float* fv_w2 = (const float*)d_in[20]; const float* fv_b2 = (const float*)d_in[21];
  u16* wtw = (u16*)d_ws;          // 10485760 B
  float* outp = (float*)d_out;

  prep_wt_k<<<dim3(128, 8, 8), dim3(256), 0, stream>>>(
      ak_w1, ak_w2, av_w1, av_w2, fk_w1, fk_w2, fv_w1, fv_w2, wtw);

  CacheFuser_73873437491748_kernel<<<dim3(1024), dim3(512), 0, stream>>>(
      recv_k, recv_v, shar_k, shar_v, ew, alpha,
      ak_b1, ak_b2, av_b1, av_b2, fk_b1, fk_b2, fv_b1, fv_b2, wtw, outp);
}

// Round 5
// 796.547 us; speedup vs baseline: 1.8959x; 1.8959x over previous
//
#include <hip/hip_runtime.h>

// CacheFuser on MI355X (gfx950) — round 5.
// Register model learned from r1-r4: MFMA accumulators live in AGPRs (cheap);
// long-lived LOAD-DESTINATION arrays are arch-VGPRs (the spill source).
//  * BM=128, 1 block/CU (2 waves/SIMD -> 256 unified regs/wave).
//  * acc[4][4] AGPR tiles (like r1, which was spill-free at VGPR=116).
//  * W direct from L2 (k-tile-major bf16 in d_ws) -> no per-kstep barriers.
//  * Staging of the next activation tile is FUSED into GEMM2's k-loop with a
//    rolling depth-3 register pipeline (24 transient arch regs, ~3-kt lead
//    to cover HBM latency). No StageRegs held across GEMMs.
//  * 12 barriers/path (vs r1's 352).

typedef unsigned int  u32;
typedef unsigned short u16;
typedef __attribute__((ext_vector_type(8))) short bf16x8;   // 8 x bf16
typedef __attribute__((ext_vector_type(4))) float f32x4;

#define LL   8
#define NN   4
#define HH   256
#define RPL  8192            // rows per layer = B*S
#define BM   128             // rows per block

// d_ws layout: per layer 655360 u16; per matrix: k-tile-major 8192-u16 tiles,
// tile kt holds W^T[p][kt*32..kt*32+32) as [p][32] row-major.
#define LSTRIDE 655360
#define O_AKW1 0
#define O_AKW2 65536
#define O_AVW1 131072
#define O_AVW2 196608
#define O_FKW1 262144        // K=512 -> 16 tiles (0..7 recv half, 8..15 agg half)
#define O_FKW2 393216
#define O_FVW1 458752
#define O_FVW2 589824
// total 5242880 u16 = 10485760 B in d_ws

__device__ __forceinline__ u32 f2bf(float f) {
  u32 u = __builtin_bit_cast(u32, f);
  return (u + 0x7fffu + ((u >> 16) & 1u)) >> 16;   // RNE
}

__device__ __forceinline__ float4 ldf4(const float* p) { return *(const float4*)p; }

// ---------------- prep: W[k][p] f32 -> k-tile-major bf16 W^T tiles -----------
__global__ __launch_bounds__(256) void prep_wt_k(
    const float* __restrict__ s0, const float* __restrict__ s1,
    const float* __restrict__ s2, const float* __restrict__ s3,
    const float* __restrict__ s4, const float* __restrict__ s5,
    const float* __restrict__ s6, const float* __restrict__ s7,
    u16* __restrict__ wt)
{
  __shared__ float tile[32][33];
  const int mat = blockIdx.z, l = blockIdx.y, t = blockIdx.x;
  const float* src; int off, K;
  switch (mat) {
    case 0: src = s0; off = O_AKW1; K = 256; break;
    case 1: src = s1; off = O_AKW2; K = 256; break;
    case 2: src = s2; off = O_AVW1; K = 256; break;
    case 3: src = s3; off = O_AVW2; K = 256; break;
    case 4: src = s4; off = O_FKW1; K = 512; break;
    case 5: src = s5; off = O_FKW2; K = 256; break;
    case 6: src = s6; off = O_FVW1; K = 512; break;
    default: src = s7; off = O_FVW2; K = 256; break;
  }
  const int ntk = K >> 5;
  if (t >= ntk * 8) return;                 // 8 p-tiles of 32
  const int tk = t % ntk, tp = t / ntk;
  src += (size_t)l * K * HH;
  u16* dst = wt + (size_t)l * LSTRIDE + off;
  #pragma unroll
  for (int i = 0; i < 4; ++i) {
    int idx = threadIdx.x + i * 256;
    int r = idx >> 5, c = idx & 31;        // r = k-local, c = p-local
    tile[r][c] = src[(size_t)(tk * 32 + r) * HH + tp * 32 + c];
  }
  __syncthreads();
  const int pl = threadIdx.x >> 3, kq = threadIdx.x & 7;
  const int p = tp * 32 + pl;
  ushort4 o;
  o.x = (u16)f2bf(tile[kq * 4 + 0][pl]);
  o.y = (u16)f2bf(tile[kq * 4 + 1][pl]);
  o.z = (u16)f2bf(tile[kq * 4 + 2][pl]);
  o.w = (u16)f2bf(tile[kq * 4 + 3][pl]);
  *(ushort4*)(dst + (size_t)tk * 8192 + p * 32 + kq * 4) = o;
}

// ---------------- main kernel helpers ---------------------------------------
__device__ __forceinline__ void zero44(f32x4 (&a)[4][4]) {
  f32x4 z = {0.f, 0.f, 0.f, 0.f};
  #pragma unroll
  for (int i = 0; i < 4; ++i)
    #pragma unroll
    for (int j = 0; j < 4; ++j) a[i][j] = z;
}

// D[p][q] += W^T[p][k] * Act[q][k] over K=256 (8 k-tiles), no barriers.
// a-frags: per-lane global loads from k-tile-major W (L2-resident).
// b-frags: swizzled LDS reads.
// STG: while computing, stream a [128][256] f32 tile (src) into dst as
// swizzled bf16, one 16KB chunk per kt, with a depth-3 register pipeline.
template<bool STG>
__device__ __forceinline__ void gemm8S(
    f32x4 (&acc)[4][4], const u16* __restrict__ wtile, const u16* __restrict__ act,
    const float* __restrict__ src, u16* __restrict__ dst,
    int tid, int wp, int wq, int lr, int g)
{
  const u16* wl = wtile + (wp * 64 + lr) * 32 + g * 8;  // +fp*512, +kt*8192
  float4 slot[3][2];                                    // rolling chunks
  if (STG) {
    #pragma unroll
    for (int c = 0; c < 3; ++c) {
      slot[c][0] = ldf4(src + (size_t)(c * 1024 + tid) * 4);
      slot[c][1] = ldf4(src + (size_t)(c * 1024 + 512 + tid) * 4);
    }
  }
  #pragma unroll
  for (int kt = 0; kt < 8; ++kt) {
    bf16x8 a[4], b[4];
    #pragma unroll
    for (int fp = 0; fp < 4; ++fp)
      a[fp] = *(const bf16x8*)(wl + kt * 8192 + fp * 512);
    #pragma unroll
    for (int fq = 0; fq < 4; ++fq) {
      int q = wq * 64 + fq * 16 + lr;
      int k = (kt * 32 + g * 8) ^ ((q & 7) << 3);
      b[fq] = *(const bf16x8*)(act + q * HH + k);
    }
    if (STG) {
      const int s = kt % 3;                 // compile-time after unroll
      #pragma unroll
      for (int h = 0; h < 2; ++h) {
        int idx = kt * 1024 + h * 512 + tid;
        int q = idx >> 6, c = (idx & 63) * 4;
        const float4& v = slot[s][h];
        ushort4 o;
        o.x = (u16)f2bf(v.x); o.y = (u16)f2bf(v.y);
        o.z = (u16)f2bf(v.z); o.w = (u16)f2bf(v.w);
        *(ushort4*)(dst + q * HH + (c ^ ((q & 7) << 3))) = o;
      }
      if (kt + 3 < 8) {
        slot[s][0] = ldf4(src + (size_t)((kt + 3) * 1024 + tid) * 4);
        slot[s][1] = ldf4(src + (size_t)((kt + 3) * 1024 + 512 + tid) * 4);
      }
    }
    #pragma unroll
    for (int fp = 0; fp < 4; ++fp)
      #pragma unroll
      for (int fq = 0; fq < 4; ++fq)
        acc[fp][fq] = __builtin_amdgcn_mfma_f32_16x16x32_bf16(a[fp], b[fq], acc[fp][fq], 0, 0, 0);
  }
}

// One-shot staging (prologue): [128][256] f32 -> swizzled bf16 LDS.
__device__ __forceinline__ void stageDirect(u16* dst, const float* __restrict__ src, int tid) {
  #pragma unroll
  for (int i = 0; i < 16; ++i) {
    int idx = i * 512 + tid;
    float4 v = ldf4(src + (size_t)idx * 4);
    int q = idx >> 6, c = (idx & 63) * 4;
    ushort4 o;
    o.x = (u16)f2bf(v.x); o.y = (u16)f2bf(v.y);
    o.z = (u16)f2bf(v.z); o.w = (u16)f2bf(v.w);
    *(ushort4*)(dst + q * HH + (c ^ ((q & 7) << 3))) = o;
  }
}

// acc -> swizzled bf16 LDS: v = [relu?](acc + bscale*bias) * post
__device__ __forceinline__ void epiLds(
    u16* buf, f32x4 (&acc)[4][4], const float* __restrict__ bias,
    float bscale, float post, bool doRelu, int wp, int wq, int lr, int g)
{
  #pragma unroll
  for (int fp = 0; fp < 4; ++fp) {
    int p0 = wp * 64 + fp * 16 + g * 4;
    float4 bv = *(const float4*)(bias + p0);
    #pragma unroll
    for (int fq = 0; fq < 4; ++fq) {
      int q = wq * 64 + fq * 16 + lr;
      float v0 = acc[fp][fq][0] + bscale * bv.x;
      float v1 = acc[fp][fq][1] + bscale * bv.y;
      float v2 = acc[fp][fq][2] + bscale * bv.z;
      float v3 = acc[fp][fq][3] + bscale * bv.w;
      if (doRelu) {
        v0 = fmaxf(v0, 0.f); v1 = fmaxf(v1, 0.f);
        v2 = fmaxf(v2, 0.f); v3 = fmaxf(v3, 0.f);
      }
      ushort4 o;
      o.x = (u16)f2bf(v0 * post); o.y = (u16)f2bf(v1 * post);
      o.z = (u16)f2bf(v2 * post); o.w = (u16)f2bf(v3 * post);
      *(ushort4*)(buf + q * HH + (p0 ^ ((q & 7) << 3))) = o;
    }
  }
}

// out = recv + gate*(acc + bias)
__device__ __forceinline__ void epiOut(
    f32x4 (&acc)[4][4], const float* __restrict__ bias,
    const float* __restrict__ recv, float* __restrict__ outp,
    float gate, int wp, int wq, int lr, int g)
{
  #pragma unroll
  for (int fp = 0; fp < 4; ++fp) {
    int p0 = wp * 64 + fp * 16 + g * 4;
    float4 bv = *(const float4*)(bias + p0);
    #pragma unroll
    for (int fq = 0; fq < 4; ++fq) {
      int q = wq * 64 + fq * 16 + lr;
      float4 rv = *(const float4*)(recv + (size_t)q * HH + p0);
      float4 ov;
      ov.x = rv.x + gate * (acc[fp][fq][0] + bv.x);
      ov.y = rv.y + gate * (acc[fp][fq][1] + bv.y);
      ov.z = rv.z + gate * (acc[fp][fq][2] + bv.z);
      ov.w = rv.w + gate * (acc[fp][fq][3] + bv.w);
      *(float4*)(outp + (size_t)q * HH + p0) = ov;
    }
  }
}

__global__ __launch_bounds__(512, 2) void CacheFuser_73873437491748_kernel(
    const float* __restrict__ recv_k, const float* __restrict__ recv_v,
    const float* __restrict__ shar_k, const float* __restrict__ shar_v,
    const float* __restrict__ ew, const float* __restrict__ alpha,
    const float* __restrict__ ak_b1, const float* __restrict__ ak_b2,
    const float* __restrict__ av_b1, const float* __restrict__ av_b2,
    const float* __restrict__ fk_b1, const float* __restrict__ fk_b2,
    const float* __restrict__ fv_b1, const float* __restrict__ fv_b2,
    const u16* __restrict__ wt, float* __restrict__ out)
{
  __shared__ u16 B0[BM * HH];   // 64 KB, swizzled (e ^= (q&7)<<3). Input tile.
  __shared__ u16 B1[BM * HH];   // 64 KB. Hidden / agg tile.

  const int bid = blockIdx.x;
  const int l = bid & 7, t = bid >> 3;          // layer <-> XCD affinity
  const int tid = threadIdx.x;
  const int w = tid >> 6, lane = tid & 63, lr = lane & 15, g = lane >> 4;
  const int wp = w & 3, wq = w >> 2;

  const size_t row0 = (size_t)t * BM;
  const u16* lw = wt + (size_t)l * LSTRIDE;
  const float gate = 1.f / (1.f + __expf(-2.f * alpha[l]));
  const float* ewl = ew + l * NN;

  #pragma unroll 1
  for (int path = 0; path < 2; ++path) {
    const float* recvB = (path ? recv_v : recv_k) + ((size_t)l * RPL + row0) * HH;
    const float* sharB = (path ? shar_v : shar_k) + ((size_t)l * NN * RPL + row0) * HH;
    const u16* W1  = lw + (path ? O_AVW1 : O_AKW1);
    const u16* W2  = lw + (path ? O_AVW2 : O_AKW2);
    const u16* FW1 = lw + (path ? O_FVW1 : O_FKW1);
    const u16* FW2 = lw + (path ? O_FVW2 : O_FKW2);
    const float* b1  = (path ? av_b1 : ak_b1) + l * HH;
    const float* b2  = (path ? av_b2 : ak_b2) + l * HH;
    const float* fb1 = (path ? fv_b1 : fk_b1) + l * HH;
    const float* fb2 = (path ? fv_b2 : fk_b2) + l * HH;
    float* outp = out + ((size_t)(path * LL + l) * RPL + row0) * HH;

    if (path == 0) stageDirect(B0, sharB, tid);        // sharer 0 (path 1: staged
                                                       // during path 0's fuse-GEMM2)
    f32x4 agg[4][4]; zero44(agg);
    float sS = 0.f;

    #pragma unroll 1
    for (int n = 0; n < NN; ++n) {
      float sn = ewl[n] * 0.25f; sS += sn;
      __syncthreads();                                 // B0 (input n) ready
      f32x4 h[4][4]; zero44(h);
      gemm8S<false>(h, W1, B0, nullptr, nullptr, tid, wp, wq, lr, g);
      epiLds(B1, h, b1, 1.f, sn, true, wp, wq, lr, g); // B1 = sn*relu(h+b1)
      __syncthreads();                                 // B1 ready; B0 free
      const float* nsrc = (n < 3) ? sharB + (size_t)(n + 1) * RPL * HH : recvB;
      // agg += W2*B1, while streaming next input -> B0
      gemm8S<true>(agg, W2, B1, nsrc, B0, tid, wp, wq, lr, g);
    }
    __syncthreads();                                   // B0 = recv ready; B1 free
    epiLds(B1, agg, b2, sS, 1.f, false, wp, wq, lr, g);// B1 = agg + sS*b2
    __syncthreads();
    f32x4 h[4][4]; zero44(h);
    gemm8S<false>(h, FW1, B0, nullptr, nullptr, tid, wp, wq, lr, g);            // recv half
    gemm8S<false>(h, FW1 + 8 * 8192, B1, nullptr, nullptr, tid, wp, wq, lr, g); // agg half
    __syncthreads();                                   // reads of B0/B1 done
    epiLds(B1, h, fb1, 1.f, 1.f, true, wp, wq, lr, g); // B1 = fuse hidden
    __syncthreads();
    f32x4 dd[4][4]; zero44(dd);
    if (path == 0) {
      // delta GEMM, while streaming V-path sharer0 -> B0
      gemm8S<true>(dd, FW2, B1, shar_v + ((size_t)l * NN * RPL + row0) * HH, B0,
                   tid, wp, wq, lr, g);
    } else {
      gemm8S<false>(dd, FW2, B1, nullptr, nullptr, tid, wp, wq, lr, g);
    }
    epiOut(dd, fb2, recvB, outp, gate, wp, wq, lr, g);
  }
}

extern "C" void kernel_launch(void* const* d_in, const int* in_sizes, int n_in,
                              void* d_out, int out_size, void* d_ws, size_t ws_size,
                              hipStream_t stream)
{
  const float* recv_k = (const float*)d_in[0];
  const float* recv_v = (const float*)d_in[1];
  const float* shar_k = (const float*)d_in[2];
  const float* shar_v = (const float*)d_in[3];
  const float* ew     = (const float*)d_in[4];
  const float* alpha  = (const float*)d_in[5];
  const float* ak_w1 = (const float*)d_in[6];  const float* ak_b1 = (const float*)d_in[7];
  const float* ak_w2 = (const float*)d_in[8];  const float* ak_b2 = (const float*)d_in[9];
  const float* av_w1 = (const float*)d_in[10]; const float* av_b1 = (const float*)d_in[11];
  const float* av_w2 = (const float*)d_in[12]; const float* av_b2 = (const float*)d_in[13];
  const float* fk_w1 = (const float*)d_in[14]; const float* fk_b1 = (const float*)d_in[15];
  const float* fk_w2 = (const float*)d_in[16]; const float* fk_b2 = (const float*)d_in[17];
  const float* fv_w1 = (const float*)d_in[18]; const float* fv_b1 = (const float*)d_in[19];
  const float* fv_w2 = (const float*)d_in[20]; const float* fv_b2 = (const float*)d_in[21];
  u16* wtw = (u16*)d_ws;          // 10485760 B
  float* outp = (float*)d_out;

  prep_wt_k<<<dim3(128, 8, 8), dim3(256), 0, stream>>>(
      ak_w1, ak_w2, av_w1, av_w2, fk_w1, fk_w2, fv_w1, fv_w2, wtw);

  CacheFuser_73873437491748_kernel<<<dim3(512), dim3(512), 0, stream>>>(
      recv_k, recv_v, shar_k, shar_v, ew, alpha,
      ak_b1, ak_b2, av_b1, av_b2, fk_b1, fk_b2, fv_b1, fv_b2, wtw, outp);
}

// Round 6
// 790.991 us; speedup vs baseline: 1.9093x; 1.0070x over previous
//
#include <hip/hip_runtime.h>

// CacheFuser on MI355X (gfx950) — round 6.
// r5 spilled (~575MB scratch) NOT from static demand (~95 arch regs) but from
// the scheduler hoisting the fully-unrolled k-loop's independent W-loads
// (up to 32 bf16x8 = 128 regs in flight) once the per-kstep barriers were
// gone. Fix: bound the scheduler, keep the structure.
//  * explicit 2-deep a-frag pipeline (a[2][4]);
//  * sched_barrier(0x38F) per kt: ALU/VALU/SALU/MFMA/DS may cross, VMEM may
//    NOT -> in-flight VMEM capped at ~40 regs;
//  * plain __launch_bounds__(512) (the spill-free r1 config).
// Everything else identical to r5 (BM=128, W direct from L2 k-tile-major,
// fused rolling depth-3 staging, 12 barriers/path).

typedef unsigned int  u32;
typedef unsigned short u16;
typedef __attribute__((ext_vector_type(8))) short bf16x8;   // 8 x bf16
typedef __attribute__((ext_vector_type(4))) float f32x4;

#define LL   8
#define NN   4
#define HH   256
#define RPL  8192            // rows per layer = B*S
#define BM   128             // rows per block

// d_ws layout: per layer 655360 u16; per matrix: k-tile-major 8192-u16 tiles,
// tile kt holds W^T[p][kt*32..kt*32+32) as [p][32] row-major.
#define LSTRIDE 655360
#define O_AKW1 0
#define O_AKW2 65536
#define O_AVW1 131072
#define O_AVW2 196608
#define O_FKW1 262144        // K=512 -> 16 tiles (0..7 recv half, 8..15 agg half)
#define O_FKW2 393216
#define O_FVW1 458752
#define O_FVW2 589824
// total 5242880 u16 = 10485760 B in d_ws

__device__ __forceinline__ u32 f2bf(float f) {
  u32 u = __builtin_bit_cast(u32, f);
  return (u + 0x7fffu + ((u >> 16) & 1u)) >> 16;   // RNE
}

__device__ __forceinline__ float4 ldf4(const float* p) { return *(const float4*)p; }

// ---------------- prep: W[k][p] f32 -> k-tile-major bf16 W^T tiles -----------
__global__ __launch_bounds__(256) void prep_wt_k(
    const float* __restrict__ s0, const float* __restrict__ s1,
    const float* __restrict__ s2, const float* __restrict__ s3,
    const float* __restrict__ s4, const float* __restrict__ s5,
    const float* __restrict__ s6, const float* __restrict__ s7,
    u16* __restrict__ wt)
{
  __shared__ float tile[32][33];
  const int mat = blockIdx.z, l = blockIdx.y, t = blockIdx.x;
  const float* src; int off, K;
  switch (mat) {
    case 0: src = s0; off = O_AKW1; K = 256; break;
    case 1: src = s1; off = O_AKW2; K = 256; break;
    case 2: src = s2; off = O_AVW1; K = 256; break;
    case 3: src = s3; off = O_AVW2; K = 256; break;
    case 4: src = s4; off = O_FKW1; K = 512; break;
    case 5: src = s5; off = O_FKW2; K = 256; break;
    case 6: src = s6; off = O_FVW1; K = 512; break;
    default: src = s7; off = O_FVW2; K = 256; break;
  }
  const int ntk = K >> 5;
  if (t >= ntk * 8) return;                 // 8 p-tiles of 32
  const int tk = t % ntk, tp = t / ntk;
  src += (size_t)l * K * HH;
  u16* dst = wt + (size_t)l * LSTRIDE + off;
  #pragma unroll
  for (int i = 0; i < 4; ++i) {
    int idx = threadIdx.x + i * 256;
    int r = idx >> 5, c = idx & 31;        // r = k-local, c = p-local
    tile[r][c] = src[(size_t)(tk * 32 + r) * HH + tp * 32 + c];
  }
  __syncthreads();
  const int pl = threadIdx.x >> 3, kq = threadIdx.x & 7;
  const int p = tp * 32 + pl;
  ushort4 o;
  o.x = (u16)f2bf(tile[kq * 4 + 0][pl]);
  o.y = (u16)f2bf(tile[kq * 4 + 1][pl]);
  o.z = (u16)f2bf(tile[kq * 4 + 2][pl]);
  o.w = (u16)f2bf(tile[kq * 4 + 3][pl]);
  *(ushort4*)(dst + (size_t)tk * 8192 + p * 32 + kq * 4) = o;
}

// ---------------- main kernel helpers ---------------------------------------
__device__ __forceinline__ void zero44(f32x4 (&a)[4][4]) {
  f32x4 z = {0.f, 0.f, 0.f, 0.f};
  #pragma unroll
  for (int i = 0; i < 4; ++i)
    #pragma unroll
    for (int j = 0; j < 4; ++j) a[i][j] = z;
}

// D[p][q] += W^T[p][k] * Act[q][k] over K=256 (8 k-tiles), no thread barriers.
// a-frags: per-lane global loads from k-tile-major W (L2), 2-deep pipeline.
// b-frags: swizzled LDS reads.
// STG: while computing, stream a [128][256] f32 tile (src) into dst as
// swizzled bf16, one 16KB chunk per kt, depth-3 register pipeline.
// sched_barrier(0x38F) per kt: VMEM may not cross iteration boundaries
// (caps register pressure); ALU/VALU/SALU/MFMA/DS may.
template<bool STG>
__device__ __forceinline__ void gemm8S(
    f32x4 (&acc)[4][4], const u16* __restrict__ wtile, const u16* __restrict__ act,
    const float* __restrict__ src, u16* __restrict__ dst,
    int tid, int wp, int wq, int lr, int g)
{
  const u16* wl = wtile + (wp * 64 + lr) * 32 + g * 8;  // +fp*512, +kt*8192
  float4 slot[3][2];                                    // rolling chunks
  if (STG) {
    #pragma unroll
    for (int c = 0; c < 3; ++c) {
      slot[c][0] = ldf4(src + (size_t)(c * 1024 + tid) * 4);
      slot[c][1] = ldf4(src + (size_t)(c * 1024 + 512 + tid) * 4);
    }
  }
  bf16x8 a[2][4];
  #pragma unroll
  for (int fp = 0; fp < 4; ++fp) a[0][fp] = *(const bf16x8*)(wl + fp * 512);
  #pragma unroll
  for (int kt = 0; kt < 8; ++kt) {
    const int cur = kt & 1;
    if (kt < 7) {
      #pragma unroll
      for (int fp = 0; fp < 4; ++fp)
        a[cur ^ 1][fp] = *(const bf16x8*)(wl + (kt + 1) * 8192 + fp * 512);
    }
    bf16x8 b[4];
    #pragma unroll
    for (int fq = 0; fq < 4; ++fq) {
      int q = wq * 64 + fq * 16 + lr;
      int k = (kt * 32 + g * 8) ^ ((q & 7) << 3);
      b[fq] = *(const bf16x8*)(act + q * HH + k);
    }
    if (STG) {
      const int s = kt % 3;                 // compile-time after unroll
      #pragma unroll
      for (int h = 0; h < 2; ++h) {
        int idx = kt * 1024 + h * 512 + tid;
        int q = idx >> 6, c = (idx & 63) * 4;
        const float4& v = slot[s][h];
        ushort4 o;
        o.x = (u16)f2bf(v.x); o.y = (u16)f2bf(v.y);
        o.z = (u16)f2bf(v.z); o.w = (u16)f2bf(v.w);
        *(ushort4*)(dst + q * HH + (c ^ ((q & 7) << 3))) = o;
      }
      if (kt + 3 < 8) {
        slot[s][0] = ldf4(src + (size_t)((kt + 3) * 1024 + tid) * 4);
        slot[s][1] = ldf4(src + (size_t)((kt + 3) * 1024 + 512 + tid) * 4);
      }
    }
    #pragma unroll
    for (int fp = 0; fp < 4; ++fp)
      #pragma unroll
      for (int fq = 0; fq < 4; ++fq)
        acc[fp][fq] = __builtin_amdgcn_mfma_f32_16x16x32_bf16(a[cur][fp], b[fq], acc[fp][fq], 0, 0, 0);
    // Block VMEM from crossing iteration boundaries (register-pressure cap);
    // allow ALU|VALU|SALU|MFMA|DS|DS_READ|DS_WRITE to interleave freely.
    __builtin_amdgcn_sched_barrier(0x38F);
  }
}

// One-shot staging (prologue): [128][256] f32 -> swizzled bf16 LDS.
__device__ __forceinline__ void stageDirect(u16* dst, const float* __restrict__ src, int tid) {
  #pragma unroll
  for (int i = 0; i < 16; ++i) {
    int idx = i * 512 + tid;
    float4 v = ldf4(src + (size_t)idx * 4);
    int q = idx >> 6, c = (idx & 63) * 4;
    ushort4 o;
    o.x = (u16)f2bf(v.x); o.y = (u16)f2bf(v.y);
    o.z = (u16)f2bf(v.z); o.w = (u16)f2bf(v.w);
    *(ushort4*)(dst + q * HH + (c ^ ((q & 7) << 3))) = o;
  }
}

// acc -> swizzled bf16 LDS: v = [relu?](acc + bscale*bias) * post
__device__ __forceinline__ void epiLds(
    u16* buf, f32x4 (&acc)[4][4], const float* __restrict__ bias,
    float bscale, float post, bool doRelu, int wp, int wq, int lr, int g)
{
  #pragma unroll
  for (int fp = 0; fp < 4; ++fp) {
    int p0 = wp * 64 + fp * 16 + g * 4;
    float4 bv = *(const float4*)(bias + p0);
    #pragma unroll
    for (int fq = 0; fq < 4; ++fq) {
      int q = wq * 64 + fq * 16 + lr;
      float v0 = acc[fp][fq][0] + bscale * bv.x;
      float v1 = acc[fp][fq][1] + bscale * bv.y;
      float v2 = acc[fp][fq][2] + bscale * bv.z;
      float v3 = acc[fp][fq][3] + bscale * bv.w;
      if (doRelu) {
        v0 = fmaxf(v0, 0.f); v1 = fmaxf(v1, 0.f);
        v2 = fmaxf(v2, 0.f); v3 = fmaxf(v3, 0.f);
      }
      ushort4 o;
      o.x = (u16)f2bf(v0 * post); o.y = (u16)f2bf(v1 * post);
      o.z = (u16)f2bf(v2 * post); o.w = (u16)f2bf(v3 * post);
      *(ushort4*)(buf + q * HH + (p0 ^ ((q & 7) << 3))) = o;
    }
  }
}

// out = recv + gate*(acc + bias)
__device__ __forceinline__ void epiOut(
    f32x4 (&acc)[4][4], const float* __restrict__ bias,
    const float* __restrict__ recv, float* __restrict__ outp,
    float gate, int wp, int wq, int lr, int g)
{
  #pragma unroll
  for (int fp = 0; fp < 4; ++fp) {
    int p0 = wp * 64 + fp * 16 + g * 4;
    float4 bv = *(const float4*)(bias + p0);
    #pragma unroll
    for (int fq = 0; fq < 4; ++fq) {
      int q = wq * 64 + fq * 16 + lr;
      float4 rv = *(const float4*)(recv + (size_t)q * HH + p0);
      float4 ov;
      ov.x = rv.x + gate * (acc[fp][fq][0] + bv.x);
      ov.y = rv.y + gate * (acc[fp][fq][1] + bv.y);
      ov.z = rv.z + gate * (acc[fp][fq][2] + bv.z);
      ov.w = rv.w + gate * (acc[fp][fq][3] + bv.w);
      *(float4*)(outp + (size_t)q * HH + p0) = ov;
    }
  }
}

__global__ __launch_bounds__(512) void CacheFuser_73873437491748_kernel(
    const float* __restrict__ recv_k, const float* __restrict__ recv_v,
    const float* __restrict__ shar_k, const float* __restrict__ shar_v,
    const float* __restrict__ ew, const float* __restrict__ alpha,
    const float* __restrict__ ak_b1, const float* __restrict__ ak_b2,
    const float* __restrict__ av_b1, const float* __restrict__ av_b2,
    const float* __restrict__ fk_b1, const float* __restrict__ fk_b2,
    const float* __restrict__ fv_b1, const float* __restrict__ fv_b2,
    const u16* __restrict__ wt, float* __restrict__ out)
{
  __shared__ u16 B0[BM * HH];   // 64 KB, swizzled (e ^= (q&7)<<3). Input tile.
  __shared__ u16 B1[BM * HH];   // 64 KB. Hidden / agg tile.

  const int bid = blockIdx.x;
  const int l = bid & 7, t = bid >> 3;          // layer <-> XCD affinity
  const int tid = threadIdx.x;
  const int w = tid >> 6, lane = tid & 63, lr = lane & 15, g = lane >> 4;
  const int wp = w & 3, wq = w >> 2;

  const size_t row0 = (size_t)t * BM;
  const u16* lw = wt + (size_t)l * LSTRIDE;
  const float gate = 1.f / (1.f + __expf(-2.f * alpha[l]));
  const float* ewl = ew + l * NN;

  #pragma unroll 1
  for (int path = 0; path < 2; ++path) {
    const float* recvB = (path ? recv_v : recv_k) + ((size_t)l * RPL + row0) * HH;
    const float* sharB = (path ? shar_v : shar_k) + ((size_t)l * NN * RPL + row0) * HH;
    const u16* W1  = lw + (path ? O_AVW1 : O_AKW1);
    const u16* W2  = lw + (path ? O_AVW2 : O_AKW2);
    const u16* FW1 = lw + (path ? O_FVW1 : O_FKW1);
    const u16* FW2 = lw + (path ? O_FVW2 : O_FKW2);
    const float* b1  = (path ? av_b1 : ak_b1) + l * HH;
    const float* b2  = (path ? av_b2 : ak_b2) + l * HH;
    const float* fb1 = (path ? fv_b1 : fk_b1) + l * HH;
    const float* fb2 = (path ? fv_b2 : fk_b2) + l * HH;
    float* outp = out + ((size_t)(path * LL + l) * RPL + row0) * HH;

    if (path == 0) stageDirect(B0, sharB, tid);        // sharer 0 (path 1: staged
                                                       // during path 0's fuse-GEMM2)
    f32x4 agg[4][4]; zero44(agg);
    float sS = 0.f;

    #pragma unroll 1
    for (int n = 0; n < NN; ++n) {
      float sn = ewl[n] * 0.25f; sS += sn;
      __syncthreads();                                 // B0 (input n) ready
      f32x4 h[4][4]; zero44(h);
      gemm8S<false>(h, W1, B0, nullptr, nullptr, tid, wp, wq, lr, g);
      epiLds(B1, h, b1, 1.f, sn, true, wp, wq, lr, g); // B1 = sn*relu(h+b1)
      __syncthreads();                                 // B1 ready; B0 free
      const float* nsrc = (n < 3) ? sharB + (size_t)(n + 1) * RPL * HH : recvB;
      // agg += W2*B1, while streaming next input -> B0
      gemm8S<true>(agg, W2, B1, nsrc, B0, tid, wp, wq, lr, g);
    }
    __syncthreads();                                   // B0 = recv ready; B1 free
    epiLds(B1, agg, b2, sS, 1.f, false, wp, wq, lr, g);// B1 = agg + sS*b2
    __syncthreads();
    f32x4 h[4][4]; zero44(h);
    gemm8S<false>(h, FW1, B0, nullptr, nullptr, tid, wp, wq, lr, g);            // recv half
    gemm8S<false>(h, FW1 + 8 * 8192, B1, nullptr, nullptr, tid, wp, wq, lr, g); // agg half
    __syncthreads();                                   // reads of B0/B1 done
    epiLds(B1, h, fb1, 1.f, 1.f, true, wp, wq, lr, g); // B1 = fuse hidden
    __syncthreads();
    f32x4 dd[4][4]; zero44(dd);
    if (path == 0) {
      // delta GEMM, while streaming V-path sharer0 -> B0
      gemm8S<true>(dd, FW2, B1, shar_v + ((size_t)l * NN * RPL + row0) * HH, B0,
                   tid, wp, wq, lr, g);
    } else {
      gemm8S<false>(dd, FW2, B1, nullptr, nullptr, tid, wp, wq, lr, g);
    }
    epiOut(dd, fb2, recvB, outp, gate, wp, wq, lr, g);
  }
}

extern "C" void kernel_launch(void* const* d_in, const int* in_sizes, int n_in,
                              void* d_out, int out_size, void* d_ws, size_t ws_size,
                              hipStream_t stream)
{
  const float* recv_k = (const float*)d_in[0];
  const float* recv_v = (const float*)d_in[1];
  const float* shar_k = (const float*)d_in[2];
  const float* shar_v = (const float*)d_in[3];
  const float* ew     = (const float*)d_in[4];
  const float* alpha  = (const float*)d_in[5];
  const float* ak_w1 = (const float*)d_in[6];  const float* ak_b1 = (const float*)d_in[7];
  const float* ak_w2 = (const float*)d_in[8];  const float* ak_b2 = (const float*)d_in[9];
  const float* av_w1 = (const float*)d_in[10]; const float* av_b1 = (const float*)d_in[11];
  const float* av_w2 = (const float*)d_in[12]; const float* av_b2 = (const float*)d_in[13];
  const float* fk_w1 = (const float*)d_in[14]; const float* fk_b1 = (const float*)d_in[15];
  const float* fk_w2 = (const float*)d_in[16]; const float* fk_b2 = (const float*)d_in[17];
  const float* fv_w1 = (const float*)d_in[18]; const float* fv_b1 = (const float*)d_in[19];
  const float* fv_w2 = (const float*)d_in[20]; const float* fv_b2 = (const float*)d_in[21];
  u16* wtw = (u16*)d_ws;          // 10485760 B
  float* outp = (float*)d_out;

  prep_wt_k<<<dim3(128, 8, 8), dim3(256), 0, stream>>>(
      ak_w1, ak_w2, av_w1, av_w2, fk_w1, fk_w2, fv_w1, fv_w2, wtw);

  CacheFuser_73873437491748_kernel<<<dim3(512), dim3(512), 0, stream>>>(
      recv_k, recv_v, shar_k, shar_v, ew, alpha,
      ak_b1, ak_b2, av_b1, av_b2, fk_b1, fk_b2, fv_b1, fv_b2, wtw, outp);
}

// Round 7
// 533.447 us; speedup vs baseline: 2.8310x; 1.4828x over previous
//
#include <hip/hip_runtime.h>

// CacheFuser on MI355X (gfx950) — round 7.
// Unified-file model (reconciles r1-r6): 256 regs/wave cap at 2 waves/SIMD;
// VGPR_Count = arch partition only. r5/r6: AGPR 128 + arch ~150 = 278 > 256
// -> unavoidable spill. Fix by ALGEBRA: GEMM2 is linear and W2 shared across
// sharers, so agg = W2 * (sum_n sn*relu(W1 x_n + b1)). Accumulate hsum in 64
// arch f32 regs, run ONE GEMM2 per path:
//   * AGPR peak 128 -> 64; total ~235 <= 256 -> no spill
//   * 27% less MFMA work (8 -> 5 align GEMMs per path)
// 2-buffer ping-pong, staging fused in k-loops, 9 barriers/path.

typedef unsigned int  u32;
typedef unsigned short u16;
typedef __attribute__((ext_vector_type(8))) short bf16x8;   // 8 x bf16
typedef __attribute__((ext_vector_type(4))) float f32x4;

#define LL   8
#define NN   4
#define HH   256
#define RPL  8192            // rows per layer = B*S
#define BM   128             // rows per block

// d_ws layout: per layer 655360 u16; per matrix: k-tile-major 8192-u16 tiles,
// tile kt holds W^T[p][kt*32..kt*32+32) as [p][32] row-major.
#define LSTRIDE 655360
#define O_AKW1 0
#define O_AKW2 65536
#define O_AVW1 131072
#define O_AVW2 196608
#define O_FKW1 262144        // K=512 -> 16 tiles (0..7 recv half, 8..15 agg half)
#define O_FKW2 393216
#define O_FVW1 458752
#define O_FVW2 589824
// total 5242880 u16 = 10485760 B in d_ws

__device__ __forceinline__ u32 f2bf(float f) {
  u32 u = __builtin_bit_cast(u32, f);
  return (u + 0x7fffu + ((u >> 16) & 1u)) >> 16;   // RNE
}

__device__ __forceinline__ float4 ldf4(const float* p) { return *(const float4*)p; }

// ---------------- prep: W[k][p] f32 -> k-tile-major bf16 W^T tiles -----------
__global__ __launch_bounds__(256) void prep_wt_k(
    const float* __restrict__ s0, const float* __restrict__ s1,
    const float* __restrict__ s2, const float* __restrict__ s3,
    const float* __restrict__ s4, const float* __restrict__ s5,
    const float* __restrict__ s6, const float* __restrict__ s7,
    u16* __restrict__ wt)
{
  __shared__ float tile[32][33];
  const int mat = blockIdx.z, l = blockIdx.y, t = blockIdx.x;
  const float* src; int off, K;
  switch (mat) {
    case 0: src = s0; off = O_AKW1; K = 256; break;
    case 1: src = s1; off = O_AKW2; K = 256; break;
    case 2: src = s2; off = O_AVW1; K = 256; break;
    case 3: src = s3; off = O_AVW2; K = 256; break;
    case 4: src = s4; off = O_FKW1; K = 512; break;
    case 5: src = s5; off = O_FKW2; K = 256; break;
    case 6: src = s6; off = O_FVW1; K = 512; break;
    default: src = s7; off = O_FVW2; K = 256; break;
  }
  const int ntk = K >> 5;
  if (t >= ntk * 8) return;                 // 8 p-tiles of 32
  const int tk = t % ntk, tp = t / ntk;
  src += (size_t)l * K * HH;
  u16* dst = wt + (size_t)l * LSTRIDE + off;
  #pragma unroll
  for (int i = 0; i < 4; ++i) {
    int idx = threadIdx.x + i * 256;
    int r = idx >> 5, c = idx & 31;        // r = k-local, c = p-local
    tile[r][c] = src[(size_t)(tk * 32 + r) * HH + tp * 32 + c];
  }
  __syncthreads();
  const int pl = threadIdx.x >> 3, kq = threadIdx.x & 7;
  const int p = tp * 32 + pl;
  ushort4 o;
  o.x = (u16)f2bf(tile[kq * 4 + 0][pl]);
  o.y = (u16)f2bf(tile[kq * 4 + 1][pl]);
  o.z = (u16)f2bf(tile[kq * 4 + 2][pl]);
  o.w = (u16)f2bf(tile[kq * 4 + 3][pl]);
  *(ushort4*)(dst + (size_t)tk * 8192 + p * 32 + kq * 4) = o;
}

// ---------------- main kernel helpers ---------------------------------------
__device__ __forceinline__ void zero44(f32x4 (&a)[4][4]) {
  f32x4 z = {0.f, 0.f, 0.f, 0.f};
  #pragma unroll
  for (int i = 0; i < 4; ++i)
    #pragma unroll
    for (int j = 0; j < 4; ++j) a[i][j] = z;
}

// D[p][q] += W^T[p][k] * Act[q][k] over K=256 (8 k-tiles), no thread barriers.
// a-frags: per-lane global loads from k-tile-major W (L2), 2-deep pipeline.
// b-frags: swizzled LDS reads.
// STG: while computing, stream a [128][256] f32 tile (src) into dst as
// swizzled bf16, one 16KB chunk per kt, depth-3 register pipeline.
// sched_barrier(0x38F) per kt: VMEM may not cross iteration boundaries.
template<bool STG>
__device__ __forceinline__ void gemm8S(
    f32x4 (&acc)[4][4], const u16* __restrict__ wtile, const u16* __restrict__ act,
    const float* __restrict__ src, u16* __restrict__ dst,
    int tid, int wp, int wq, int lr, int g)
{
  const u16* wl = wtile + (wp * 64 + lr) * 32 + g * 8;  // +fp*512, +kt*8192
  float4 slot[3][2];                                    // rolling chunks
  if (STG) {
    #pragma unroll
    for (int c = 0; c < 3; ++c) {
      slot[c][0] = ldf4(src + (size_t)(c * 1024 + tid) * 4);
      slot[c][1] = ldf4(src + (size_t)(c * 1024 + 512 + tid) * 4);
    }
  }
  bf16x8 a[2][4];
  #pragma unroll
  for (int fp = 0; fp < 4; ++fp) a[0][fp] = *(const bf16x8*)(wl + fp * 512);
  #pragma unroll
  for (int kt = 0; kt < 8; ++kt) {
    const int cur = kt & 1;
    if (kt < 7) {
      #pragma unroll
      for (int fp = 0; fp < 4; ++fp)
        a[cur ^ 1][fp] = *(const bf16x8*)(wl + (kt + 1) * 8192 + fp * 512);
    }
    bf16x8 b[4];
    #pragma unroll
    for (int fq = 0; fq < 4; ++fq) {
      int q = wq * 64 + fq * 16 + lr;
      int k = (kt * 32 + g * 8) ^ ((q & 7) << 3);
      b[fq] = *(const bf16x8*)(act + q * HH + k);
    }
    if (STG) {
      const int s = kt % 3;                 // compile-time after unroll
      #pragma unroll
      for (int h = 0; h < 2; ++h) {
        int idx = kt * 1024 + h * 512 + tid;
        int q = idx >> 6, c = (idx & 63) * 4;
        const float4& v = slot[s][h];
        ushort4 o;
        o.x = (u16)f2bf(v.x); o.y = (u16)f2bf(v.y);
        o.z = (u16)f2bf(v.z); o.w = (u16)f2bf(v.w);
        *(ushort4*)(dst + q * HH + (c ^ ((q & 7) << 3))) = o;
      }
      if (kt + 3 < 8) {
        slot[s][0] = ldf4(src + (size_t)((kt + 3) * 1024 + tid) * 4);
        slot[s][1] = ldf4(src + (size_t)((kt + 3) * 1024 + 512 + tid) * 4);
      }
    }
    #pragma unroll
    for (int fp = 0; fp < 4; ++fp)
      #pragma unroll
      for (int fq = 0; fq < 4; ++fq)
        acc[fp][fq] = __builtin_amdgcn_mfma_f32_16x16x32_bf16(a[cur][fp], b[fq], acc[fp][fq], 0, 0, 0);
    __builtin_amdgcn_sched_barrier(0x38F);
  }
}

// hsum += sn * relu(h + b1)   (pure registers; bias indexed like epiLds)
__device__ __forceinline__ void hsumUpd(
    f32x4 (&hs)[4][4], f32x4 (&h)[4][4], const float* __restrict__ b1,
    float sn, int wp, int g)
{
  #pragma unroll
  for (int fp = 0; fp < 4; ++fp) {
    int p0 = wp * 64 + fp * 16 + g * 4;
    float4 bv = *(const float4*)(b1 + p0);
    #pragma unroll
    for (int fq = 0; fq < 4; ++fq) {
      hs[fp][fq][0] += sn * fmaxf(h[fp][fq][0] + bv.x, 0.f);
      hs[fp][fq][1] += sn * fmaxf(h[fp][fq][1] + bv.y, 0.f);
      hs[fp][fq][2] += sn * fmaxf(h[fp][fq][2] + bv.z, 0.f);
      hs[fp][fq][3] += sn * fmaxf(h[fp][fq][3] + bv.w, 0.f);
    }
  }
}

// One-shot staging (prologue): [128][256] f32 -> swizzled bf16 LDS.
__device__ __forceinline__ void stageDirect(u16* dst, const float* __restrict__ src, int tid) {
  #pragma unroll
  for (int i = 0; i < 16; ++i) {
    int idx = i * 512 + tid;
    float4 v = ldf4(src + (size_t)idx * 4);
    int q = idx >> 6, c = (idx & 63) * 4;
    ushort4 o;
    o.x = (u16)f2bf(v.x); o.y = (u16)f2bf(v.y);
    o.z = (u16)f2bf(v.z); o.w = (u16)f2bf(v.w);
    *(ushort4*)(dst + q * HH + (c ^ ((q & 7) << 3))) = o;
  }
}

// acc -> swizzled bf16 LDS: v = [relu?](acc + bscale*bias) * post
__device__ __forceinline__ void epiLds(
    u16* buf, f32x4 (&acc)[4][4], const float* __restrict__ bias,
    float bscale, float post, bool doRelu, int wp, int wq, int lr, int g)
{
  #pragma unroll
  for (int fp = 0; fp < 4; ++fp) {
    int p0 = wp * 64 + fp * 16 + g * 4;
    float4 bv = *(const float4*)(bias + p0);
    #pragma unroll
    for (int fq = 0; fq < 4; ++fq) {
      int q = wq * 64 + fq * 16 + lr;
      float v0 = acc[fp][fq][0] + bscale * bv.x;
      float v1 = acc[fp][fq][1] + bscale * bv.y;
      float v2 = acc[fp][fq][2] + bscale * bv.z;
      float v3 = acc[fp][fq][3] + bscale * bv.w;
      if (doRelu) {
        v0 = fmaxf(v0, 0.f); v1 = fmaxf(v1, 0.f);
        v2 = fmaxf(v2, 0.f); v3 = fmaxf(v3, 0.f);
      }
      ushort4 o;
      o.x = (u16)f2bf(v0 * post); o.y = (u16)f2bf(v1 * post);
      o.z = (u16)f2bf(v2 * post); o.w = (u16)f2bf(v3 * post);
      *(ushort4*)(buf + q * HH + (p0 ^ ((q & 7) << 3))) = o;
    }
  }
}

// out = recv + gate*(acc + bias)
__device__ __forceinline__ void epiOut(
    f32x4 (&acc)[4][4], const float* __restrict__ bias,
    const float* __restrict__ recv, float* __restrict__ outp,
    float gate, int wp, int wq, int lr, int g)
{
  #pragma unroll
  for (int fp = 0; fp < 4; ++fp) {
    int p0 = wp * 64 + fp * 16 + g * 4;
    float4 bv = *(const float4*)(bias + p0);
    #pragma unroll
    for (int fq = 0; fq < 4; ++fq) {
      int q = wq * 64 + fq * 16 + lr;
      float4 rv = *(const float4*)(recv + (size_t)q * HH + p0);
      float4 ov;
      ov.x = rv.x + gate * (acc[fp][fq][0] + bv.x);
      ov.y = rv.y + gate * (acc[fp][fq][1] + bv.y);
      ov.z = rv.z + gate * (acc[fp][fq][2] + bv.z);
      ov.w = rv.w + gate * (acc[fp][fq][3] + bv.w);
      *(float4*)(outp + (size_t)q * HH + p0) = ov;
    }
  }
}

__global__ __launch_bounds__(512) void CacheFuser_73873437491748_kernel(
    const float* __restrict__ recv_k, const float* __restrict__ recv_v,
    const float* __restrict__ shar_k, const float* __restrict__ shar_v,
    const float* __restrict__ ew, const float* __restrict__ alpha,
    const float* __restrict__ ak_b1, const float* __restrict__ ak_b2,
    const float* __restrict__ av_b1, const float* __restrict__ av_b2,
    const float* __restrict__ fk_b1, const float* __restrict__ fk_b2,
    const float* __restrict__ fv_b1, const float* __restrict__ fv_b2,
    const u16* __restrict__ wt, float* __restrict__ out)
{
  __shared__ u16 B0[BM * HH];   // 64 KB, swizzled (e ^= (q&7)<<3)
  __shared__ u16 B1[BM * HH];   // 64 KB

  const int bid = blockIdx.x;
  const int l = bid & 7, t = bid >> 3;          // layer <-> XCD affinity
  const int tid = threadIdx.x;
  const int w = tid >> 6, lane = tid & 63, lr = lane & 15, g = lane >> 4;
  const int wp = w & 3, wq = w >> 2;

  const size_t row0 = (size_t)t * BM;
  const u16* lw = wt + (size_t)l * LSTRIDE;
  const float gate = 1.f / (1.f + __expf(-2.f * alpha[l]));
  const float* ewl = ew + l * NN;

  int cur = 0;
  stageDirect(B0, shar_k + ((size_t)l * NN * RPL + row0) * HH, tid);  // K sharer0

  #pragma unroll 1
  for (int path = 0; path < 2; ++path) {
    const float* recvB = (path ? recv_v : recv_k) + ((size_t)l * RPL + row0) * HH;
    const float* sharB = (path ? shar_v : shar_k) + ((size_t)l * NN * RPL + row0) * HH;
    const u16* W1  = lw + (path ? O_AVW1 : O_AKW1);
    const u16* W2  = lw + (path ? O_AVW2 : O_AKW2);
    const u16* FW1 = lw + (path ? O_FVW1 : O_FKW1);
    const u16* FW2 = lw + (path ? O_FVW2 : O_FKW2);
    const float* b1  = (path ? av_b1 : ak_b1) + l * HH;
    const float* b2  = (path ? av_b2 : ak_b2) + l * HH;
    const float* fb1 = (path ? fv_b1 : fk_b1) + l * HH;
    const float* fb2 = (path ? fv_b2 : fk_b2) + l * HH;
    float* outp = out + ((size_t)(path * LL + l) * RPL + row0) * HH;

    f32x4 hsum[4][4]; zero44(hsum);
    float sS = 0.f;

    #pragma unroll 1
    for (int n = 0; n < NN; ++n) {
      float sn = ewl[n] * 0.25f; sS += sn;
      __syncthreads();                                // input n ready in cur
      u16* XC = cur ? B1 : B0;
      u16* XO = cur ? B0 : B1;
      const float* nsrc = (n < 3) ? sharB + (size_t)(n + 1) * RPL * HH : recvB;
      f32x4 h[4][4]; zero44(h);
      gemm8S<true>(h, W1, XC, nsrc, XO, tid, wp, wq, lr, g);
      hsumUpd(hsum, h, b1, sn, wp, g);                // pure-reg accumulate
      cur ^= 1;
    }
    // cur = recv buffer; other = dead last-sharer buffer
    u16* XR = cur ? B1 : B0;
    u16* XO = cur ? B0 : B1;
    __syncthreads();                                  // n=3 reads done, recv staged
    epiLds(XO, hsum, b1, 0.f, 1.f, false, wp, wq, lr, g);   // XO = bf16(hsum)
    __syncthreads();
    f32x4 agg[4][4]; zero44(agg);
    gemm8S<false>(agg, W2, XO, nullptr, nullptr, tid, wp, wq, lr, g);  // ONE GEMM2
    __syncthreads();
    epiLds(XO, agg, b2, sS, 1.f, false, wp, wq, lr, g);     // XO = agg + sS*b2
    __syncthreads();
    f32x4 h2[4][4]; zero44(h2);
    gemm8S<false>(h2, FW1, XR, nullptr, nullptr, tid, wp, wq, lr, g);            // recv half
    gemm8S<false>(h2, FW1 + 8 * 8192, XO, nullptr, nullptr, tid, wp, wq, lr, g); // agg half
    __syncthreads();
    epiLds(XR, h2, fb1, 1.f, 1.f, true, wp, wq, lr, g);     // XR = fuse hidden
    __syncthreads();
    f32x4 dd[4][4]; zero44(dd);
    if (path == 0) {
      // delta GEMM while streaming V-path sharer0 -> XO
      gemm8S<true>(dd, FW2, XR, shar_v + ((size_t)l * NN * RPL + row0) * HH, XO,
                   tid, wp, wq, lr, g);
    } else {
      gemm8S<false>(dd, FW2, XR, nullptr, nullptr, tid, wp, wq, lr, g);
    }
    epiOut(dd, fb2, recvB, outp, gate, wp, wq, lr, g);
    cur ^= 1;                                         // path1 input sits in XO
  }
}

extern "C" void kernel_launch(void* const* d_in, const int* in_sizes, int n_in,
                              void* d_out, int out_size, void* d_ws, size_t ws_size,
                              hipStream_t stream)
{
  const float* recv_k = (const float*)d_in[0];
  const float* recv_v = (const float*)d_in[1];
  const float* shar_k = (const float*)d_in[2];
  const float* shar_v = (const float*)d_in[3];
  const float* ew     = (const float*)d_in[4];
  const float* alpha  = (const float*)d_in[5];
  const float* ak_w1 = (const float*)d_in[6];  const float* ak_b1 = (const float*)d_in[7];
  const float* ak_w2 = (const float*)d_in[8];  const float* ak_b2 = (const float*)d_in[9];
  const float* av_w1 = (const float*)d_in[10]; const float* av_b1 = (const float*)d_in[11];
  const float* av_w2 = (const float*)d_in[12]; const float* av_b2 = (const float*)d_in[13];
  const float* fk_w1 = (const float*)d_in[14]; const float* fk_b1 = (const float*)d_in[15];
  const float* fk_w2 = (const float*)d_in[16]; const float* fk_b2 = (const float*)d_in[17];
  const float* fv_w1 = (const float*)d_in[18]; const float* fv_b1 = (const float*)d_in[19];
  const float* fv_w2 = (const float*)d_in[20]; const float* fv_b2 = (const float*)d_in[21];
  u16* wtw = (u16*)d_ws;          // 10485760 B
  float* outp = (float*)d_out;

  prep_wt_k<<<dim3(128, 8, 8), dim3(256), 0, stream>>>(
      ak_w1, ak_w2, av_w1, av_w2, fk_w1, fk_w2, fv_w1, fv_w2, wtw);

  CacheFuser_73873437491748_kernel<<<dim3(512), dim3(512), 0, stream>>>(
      recv_k, recv_v, shar_k, shar_v, ew, alpha,
      ak_b1, ak_b2, av_b1, av_b2, fk_b1, fk_b2, fv_b1, fv_b2, wtw, outp);
}